// Round 1
// baseline (750.383 us; speedup 1.0000x reference)
//
#include <hip/hip_runtime.h>

// ---------------- helpers ----------------
__device__ __forceinline__ unsigned short f2bf(float f) {
  unsigned u = __float_as_uint(f);
  u += 0x7fffu + ((u >> 16) & 1u);          // round-to-nearest-even
  return (unsigned short)(u >> 16);
}
__device__ __forceinline__ float tanh_fast(float x) {
  // tanh(x) = 1 - 2/(exp(2x)+1); saturates correctly at +-inf
  return 1.0f - 2.0f / (__expf(2.0f * x) + 1.0f);
}

// ---------------- K1: quantum sim + q-moment reduction ----------------
// writes q (B x 4) and atomically accumulates sum(q) [4] + sum(q x q) upper-tri [10]
__global__ __launch_bounds__(256) void k_quantum(
    const float4* __restrict__ x, const float* __restrict__ qp,
    float4* __restrict__ qout, float* __restrict__ stats)
{
  int tid = threadIdx.x;
  size_t r = (size_t)blockIdx.x * 256 + tid;
  float4 xr = x[r];
  float xv[4] = {xr.x, xr.y, xr.z, xr.w};

  float re[16], im[16];
#pragma unroll
  for (int i = 0; i < 16; i++) { re[i] = 0.f; im[i] = 0.f; }
  re[0] = 1.f;

#pragma unroll
  for (int d = 0; d < 3; d++) {
    // RY(x_i + theta) on each qubit. qubit q <-> bit (3-q) of flat index.
#pragma unroll
    for (int q = 0; q < 4; q++) {
      float th = 0.5f * (xv[q] + qp[d * 8 + q]);
      float s, c; __sincosf(th, &s, &c);
      int m = 8 >> q;
#pragma unroll
      for (int i = 0; i < 16; i++) if (!(i & m)) {
        int i1 = i | m;
        float r0 = re[i], i0 = im[i], r1 = re[i1], i1v = im[i1];
        re[i]  = c * r0 - s * r1;  im[i]  = c * i0 - s * i1v;
        re[i1] = s * r0 + c * r1;  im[i1] = s * i0 + c * i1v;
      }
    }
    // CNOT ring (0,1),(1,2),(2,3),(3,0) applied sequentially
#pragma unroll
    for (int q = 0; q < 4; q++) {
      int mc = 8 >> q, mt = 8 >> ((q + 1) & 3);
#pragma unroll
      for (int i = 0; i < 16; i++) if ((i & mc) && !(i & mt)) {
        int i1 = i | mt;
        float tr = re[i]; re[i] = re[i1]; re[i1] = tr;
        float ti = im[i]; im[i] = im[i1]; im[i1] = ti;
      }
    }
    // RZ(theta): amp *= e^{-i th/2} (bit=0) / e^{+i th/2} (bit=1)
#pragma unroll
    for (int q = 0; q < 4; q++) {
      float th = 0.5f * qp[d * 8 + 4 + q];
      float s, c; __sincosf(th, &s, &c);
      int m = 8 >> q;
#pragma unroll
      for (int i = 0; i < 16; i++) {
        float pi = (i & m) ? s : -s;
        float r0 = re[i], i0 = im[i];
        re[i] = r0 * c - i0 * pi;
        im[i] = r0 * pi + i0 * c;
      }
    }
  }

  float p[16];
#pragma unroll
  for (int i = 0; i < 16; i++) p[i] = re[i] * re[i] + im[i] * im[i];
  float z[4];
#pragma unroll
  for (int q = 0; q < 4; q++) {
    int m = 8 >> q; float acc = 0.f;
#pragma unroll
    for (int i = 0; i < 16; i++) acc += (i & m) ? -p[i] : p[i];
    z[q] = acc;
  }
  qout[r] = make_float4(z[0], z[1], z[2], z[3]);

  // 14 batch moments: z0..z3, then upper-tri z_a*z_b
  float st[14];
  st[0] = z[0]; st[1] = z[1]; st[2] = z[2]; st[3] = z[3];
  int p5 = 4;
#pragma unroll
  for (int a = 0; a < 4; a++)
#pragma unroll
    for (int b = a; b < 4; b++) st[p5++] = z[a] * z[b];

  __shared__ float part[4][14];
  int lane = tid & 63, wv = tid >> 6;
#pragma unroll
  for (int s = 0; s < 14; s++) {
    float v = st[s];
#pragma unroll
    for (int o = 32; o; o >>= 1) v += __shfl_down(v, o, 64);
    if (lane == 0) part[wv][s] = v;
  }
  __syncthreads();
  if (tid < 14)
    atomicAdd(stats + tid, part[0][tid] + part[1][tid] + part[2][tid] + part[3][tid]);
}

// ---------------- K2: fold BN1 into effective fc1 weights ----------------
__global__ void k_prep1(const float* __restrict__ w1, const float* __restrict__ b1,
                        const float* __restrict__ g, const float* __restrict__ bb,
                        const float* __restrict__ stats, float* __restrict__ w1e,
                        float* __restrict__ b1e, float invB)
{
  int j = threadIdx.x;   // 128
  float qb0 = stats[0] * invB, qb1 = stats[1] * invB, qb2 = stats[2] * invB, qb3 = stats[3] * invB;
  float M00 = stats[4] * invB, M01 = stats[5] * invB, M02 = stats[6] * invB, M03 = stats[7] * invB;
  float M11 = stats[8] * invB, M12 = stats[9] * invB, M13 = stats[10] * invB;
  float M22 = stats[11] * invB, M23 = stats[12] * invB, M33 = stats[13] * invB;
  float w0 = w1[j * 4 + 0], wv1 = w1[j * 4 + 1], wv2 = w1[j * 4 + 2], wv3 = w1[j * 4 + 3];
  float b = b1[j];
  float wq = w0 * qb0 + wv1 * qb1 + wv2 * qb2 + wv3 * qb3;
  float m = wq + b;
  float quad = w0 * w0 * M00 + wv1 * wv1 * M11 + wv2 * wv2 * M22 + wv3 * wv3 * M33
             + 2.f * (w0 * wv1 * M01 + w0 * wv2 * M02 + w0 * wv3 * M03
                    + wv1 * wv2 * M12 + wv1 * wv3 * M13 + wv2 * wv3 * M23);
  float e2 = quad + 2.f * b * wq + b * b;
  float var = e2 - m * m;                   // biased, matches jnp.var
  float s = g[j] * rsqrtf(var + 1e-5f);
  w1e[j * 4 + 0] = s * w0; w1e[j * 4 + 1] = s * wv1;
  w1e[j * 4 + 2] = s * wv2; w1e[j * 4 + 3] = s * wv3;
  b1e[j] = s * b + bb[j] - s * m;
}

// ---------------- K3: h2 batch stats (sum, sumsq per feature) ----------------
__global__ __launch_bounds__(256) void k_fc2stats(
    const float4* __restrict__ q, const float4* __restrict__ w1e4,
    const float* __restrict__ b1e, const float* __restrict__ w2,
    const float* __restrict__ b2, float* __restrict__ s2sum, float* __restrict__ s2sq)
{
  __shared__ float ssum[256], ssq[256];
  int t = threadIdx.x;
  ssum[t] = 0.f; ssq[t] = 0.f;
  __syncthreads();

  size_t r = (size_t)blockIdx.x * 256 + t;
  float4 qv = q[r];
  float act[128];
#pragma unroll
  for (int j = 0; j < 128; j++) {
    float4 w = w1e4[j];
    float v = b1e[j] + w.x * qv.x + w.y * qv.y + w.z * qv.z + w.w * qv.w;
    act[j] = fmaxf(v, 0.f);
  }

  int lane = t & 63;
#pragma unroll 1
  for (int j = 0; j < 256; j += 2) {
    const float* __restrict__ wa = w2 + (size_t)j * 128;  // lane-uniform -> s_load
    float pa0 = 0.f, pa1 = 0.f, pa2 = 0.f, pa3 = 0.f;
    float pb0 = 0.f, pb1 = 0.f, pb2 = 0.f, pb3 = 0.f;
#pragma unroll
    for (int k = 0; k < 128; k += 4) {
      pa0 = fmaf(wa[k + 0], act[k + 0], pa0);
      pa1 = fmaf(wa[k + 1], act[k + 1], pa1);
      pa2 = fmaf(wa[k + 2], act[k + 2], pa2);
      pa3 = fmaf(wa[k + 3], act[k + 3], pa3);
      pb0 = fmaf(wa[128 + k + 0], act[k + 0], pb0);
      pb1 = fmaf(wa[128 + k + 1], act[k + 1], pb1);
      pb2 = fmaf(wa[128 + k + 2], act[k + 2], pb2);
      pb3 = fmaf(wa[128 + k + 3], act[k + 3], pb3);
    }
    float ha = b2[j] + ((pa0 + pa1) + (pa2 + pa3));
    float hb = b2[j + 1] + ((pb0 + pb1) + (pb2 + pb3));
    float sa = ha, qa = ha * ha, sb = hb, qb = hb * hb;
#pragma unroll
    for (int o = 32; o; o >>= 1) {
      sa += __shfl_down(sa, o, 64);
      qa += __shfl_down(qa, o, 64);
      sb += __shfl_down(sb, o, 64);
      qb += __shfl_down(qb, o, 64);
    }
    if (lane == 0) {
      atomicAdd(&ssum[j], sa);     atomicAdd(&ssq[j], qa);
      atomicAdd(&ssum[j + 1], sb); atomicAdd(&ssq[j + 1], qb);
    }
  }
  __syncthreads();
  atomicAdd(s2sum + t, ssum[t]);
  atomicAdd(s2sq + t, ssq[t]);
}

// ---------------- K4: BN2 affine coefficients ----------------
__global__ void k_prep2(const float* __restrict__ g, const float* __restrict__ bb,
                        const float* __restrict__ s2sum, const float* __restrict__ s2sq,
                        float* __restrict__ sc2, float* __restrict__ t2, float invB)
{
  int j = threadIdx.x;   // 256
  float m = s2sum[j] * invB;
  float v = s2sq[j] * invB - m * m;
  float s = g[j] * rsqrtf(v + 1e-5f);
  sc2[j] = s;
  t2[j] = bb[j] - m * s;
}

// ---------------- K5: a1 -> h2 -> a2 (LDS, bf16) -> fc3 -> tanh -> out ----------------
__global__ __launch_bounds__(256) void k_final(
    const float4* __restrict__ q, const float4* __restrict__ w1e4,
    const float* __restrict__ b1e, const float* __restrict__ sc2,
    const float* __restrict__ t2g, const float* __restrict__ w2,
    const float* __restrict__ b2, const float* __restrict__ w3,
    const float* __restrict__ b3, float* __restrict__ out)
{
  __shared__ __align__(16) float4 qs[64];                 // 1 KB
  __shared__ __align__(16) float a1s[32][128];            // 16 KB (reused per 32-row half)
  __shared__ __align__(16) unsigned short a2s[64][256];   // 32 KB, bf16

  int t = threadIdx.x;
  int lane = t & 63, wv = t >> 6;

  if (t < 64) qs[t] = q[(size_t)blockIdx.x * 64 + t];

  int jc[4]; float s2v[4], t2v[4];
#pragma unroll
  for (int c = 0; c < 4; c++) {
    jc[c] = lane + 64 * c;
    s2v[c] = sc2[jc[c]];
    t2v[c] = t2g[jc[c]];
  }
  int ja = t & 127;
  float4 w1 = w1e4[ja];
  float b1v = b1e[ja];
  int rr = t >> 7;
  __syncthreads();

  for (int h = 0; h < 2; ++h) {
    // ---- A1: a1 for 32 rows (rows h*32 .. h*32+31) ----
#pragma unroll
    for (int i = 0; i < 16; i++) {
      int r = rr * 16 + i;
      float4 qv = qs[h * 32 + r];                         // wave-uniform -> broadcast
      float v = b1v + w1.x * qv.x + w1.y * qv.y + w1.z * qv.z + w1.w * qv.w;
      a1s[r][ja] = fmaxf(v, 0.f);
    }
    __syncthreads();

    // ---- A2: h2 = W2 a1 + b2 for 32 rows x 256 cols, K=128; bn2+relu -> a2s (bf16)
    {
      int r0 = wv * 8;
      float acc[8][4];
#pragma unroll
      for (int c = 0; c < 4; c++) {
        float bc = b2[jc[c]];
#pragma unroll
        for (int ri = 0; ri < 8; ri++) acc[ri][c] = bc;
      }
#pragma unroll 2
      for (int k4 = 0; k4 < 32; k4++) {
        float4 wv4[4];
#pragma unroll
        for (int c = 0; c < 4; c++)
          wv4[c] = *(const float4*)(w2 + (size_t)jc[c] * 128 + k4 * 4);
#pragma unroll
        for (int ri = 0; ri < 8; ri++) {
          float4 av = *(const float4*)&a1s[r0 + ri][k4 * 4]; // wave-uniform broadcast
#pragma unroll
          for (int c = 0; c < 4; c++) {
            acc[ri][c] = fmaf(av.x, wv4[c].x, acc[ri][c]);
            acc[ri][c] = fmaf(av.y, wv4[c].y, acc[ri][c]);
            acc[ri][c] = fmaf(av.z, wv4[c].z, acc[ri][c]);
            acc[ri][c] = fmaf(av.w, wv4[c].w, acc[ri][c]);
          }
        }
      }
#pragma unroll
      for (int ri = 0; ri < 8; ri++)
#pragma unroll
        for (int c = 0; c < 4; c++) {
          float a2 = fmaxf(fmaf(acc[ri][c], s2v[c], t2v[c]), 0.f);
          a2s[h * 32 + r0 + ri][jc[c]] = f2bf(a2);
        }
    }
    __syncthreads();
  }

  // ---- B: out = tanh(W3 a2 + b3), 64 rows x 256 cols, K=256 (bf16 from LDS)
  {
    int r0 = wv * 16;
    float acc[16][4];
#pragma unroll
    for (int c = 0; c < 4; c++) {
      float bc = b3[jc[c]];
#pragma unroll
      for (int ri = 0; ri < 16; ri++) acc[ri][c] = bc;
    }
#pragma unroll 1
    for (int k4 = 0; k4 < 64; k4++) {
      float4 wv4[4];
#pragma unroll
      for (int c = 0; c < 4; c++)
        wv4[c] = *(const float4*)(w3 + (size_t)jc[c] * 256 + k4 * 4);
#pragma unroll
      for (int ri = 0; ri < 16; ri++) {
        uint2 u = *(const uint2*)&a2s[r0 + ri][k4 * 4];    // wave-uniform broadcast
        float a0 = __uint_as_float(u.x << 16);
        float a1 = __uint_as_float(u.x & 0xffff0000u);
        float a2 = __uint_as_float(u.y << 16);
        float a3 = __uint_as_float(u.y & 0xffff0000u);
#pragma unroll
        for (int c = 0; c < 4; c++) {
          acc[ri][c] = fmaf(a0, wv4[c].x, acc[ri][c]);
          acc[ri][c] = fmaf(a1, wv4[c].y, acc[ri][c]);
          acc[ri][c] = fmaf(a2, wv4[c].z, acc[ri][c]);
          acc[ri][c] = fmaf(a3, wv4[c].w, acc[ri][c]);
        }
      }
    }
    size_t rowBase = (size_t)blockIdx.x * 64 + r0;
#pragma unroll
    for (int ri = 0; ri < 16; ri++) {
      float* o = out + (rowBase + ri) * 256;
#pragma unroll
      for (int c = 0; c < 4; c++) o[jc[c]] = tanh_fast(acc[ri][c]);
    }
  }
}

// ---------------- host launcher ----------------
extern "C" void kernel_launch(void* const* d_in, const int* in_sizes, int n_in,
                              void* d_out, int out_size, void* d_ws, size_t ws_size,
                              hipStream_t stream) {
  const float* x     = (const float*)d_in[0];
  const float* qp    = (const float*)d_in[1];
  const float* fc1_w = (const float*)d_in[2];
  const float* fc1_b = (const float*)d_in[3];
  const float* bn1_g = (const float*)d_in[4];
  const float* bn1_b = (const float*)d_in[5];
  const float* fc2_w = (const float*)d_in[6];
  const float* fc2_b = (const float*)d_in[7];
  const float* bn2_g = (const float*)d_in[8];
  const float* bn2_b = (const float*)d_in[9];
  const float* fc3_w = (const float*)d_in[10];
  const float* fc3_b = (const float*)d_in[11];
  float* out = (float*)d_out;
  float* ws  = (float*)d_ws;

  int B = in_sizes[0] / 4;

  // ws layout (floats): q[B*4] | stats1[16] | w1eff[512] | b1eff[128] |
  //                     s2sum[256] | s2sq[256] | sc2[256] | t2[256]
  float* wq    = ws;
  float* s1    = ws + (size_t)4 * B;
  float* w1e   = s1 + 16;
  float* b1e   = w1e + 512;
  float* s2sum = b1e + 128;
  float* s2sq  = s2sum + 256;
  float* sc2   = s2sq + 256;
  float* t2    = sc2 + 256;

  // zero the accumulator region (stats1 .. s2sq end = 16+512+128+256+256 floats)
  hipMemsetAsync((void*)s1, 0, (16 + 512 + 128 + 256 + 256) * sizeof(float), stream);

  float invB = 1.0f / (float)B;

  k_quantum<<<B / 256, 256, 0, stream>>>((const float4*)x, qp, (float4*)wq, s1);
  k_prep1<<<1, 128, 0, stream>>>(fc1_w, fc1_b, bn1_g, bn1_b, s1, w1e, b1e, invB);
  k_fc2stats<<<B / 256, 256, 0, stream>>>((const float4*)wq, (const float4*)w1e, b1e,
                                          fc2_w, fc2_b, s2sum, s2sq);
  k_prep2<<<1, 256, 0, stream>>>(bn2_g, bn2_b, s2sum, s2sq, sc2, t2, invB);
  k_final<<<B / 64, 256, 0, stream>>>((const float4*)wq, (const float4*)w1e, b1e,
                                      sc2, t2, fc2_w, fc2_b, fc3_w, fc3_b, out);
}

// Round 2
// 201.323 us; speedup vs baseline: 3.7273x; 3.7273x over previous
//
#include <hip/hip_runtime.h>

typedef __attribute__((ext_vector_type(8))) short bf16x8;
typedef __attribute__((ext_vector_type(4))) float f32x4;

// ---------------- helpers ----------------
__device__ __forceinline__ unsigned short f2bf(float f) {
  unsigned u = __float_as_uint(f);
  u += 0x7fffu + ((u >> 16) & 1u);          // round-to-nearest-even
  return (unsigned short)(u >> 16);
}
__device__ __forceinline__ float bf2f(unsigned short h) {
  return __uint_as_float((unsigned)h << 16);
}
__device__ __forceinline__ void split2(float v, unsigned short* hi, unsigned short* lo) {
  unsigned short h = f2bf(v);
  *hi = h;
  *lo = f2bf(v - bf2f(h));
}
__device__ __forceinline__ float tanh_fast(float x) {
  return 1.0f - 2.0f / (__expf(2.0f * x) + 1.0f);
}
__device__ __forceinline__ bf16x8 ldg_frag(const unsigned short* p) {
  return *(const bf16x8*)p;
}

#define MFMA(a, b, c) __builtin_amdgcn_mfma_f32_16x16x32_bf16((a), (b), (c), 0, 0, 0)

// ---------------- K1: quantum sim + q-moment reduction ----------------
__global__ __launch_bounds__(256) void k_quantum(
    const float4* __restrict__ x, const float* __restrict__ qp,
    float4* __restrict__ qout, float* __restrict__ stats)
{
  int tid = threadIdx.x;
  size_t r = (size_t)blockIdx.x * 256 + tid;
  float4 xr = x[r];
  float xv[4] = {xr.x, xr.y, xr.z, xr.w};

  float re[16], im[16];
#pragma unroll
  for (int i = 0; i < 16; i++) { re[i] = 0.f; im[i] = 0.f; }
  re[0] = 1.f;

#pragma unroll
  for (int d = 0; d < 3; d++) {
#pragma unroll
    for (int q = 0; q < 4; q++) {
      float th = 0.5f * (xv[q] + qp[d * 8 + q]);
      float s, c; __sincosf(th, &s, &c);
      int m = 8 >> q;
#pragma unroll
      for (int i = 0; i < 16; i++) if (!(i & m)) {
        int i1 = i | m;
        float r0 = re[i], i0 = im[i], r1 = re[i1], i1v = im[i1];
        re[i]  = c * r0 - s * r1;  im[i]  = c * i0 - s * i1v;
        re[i1] = s * r0 + c * r1;  im[i1] = s * i0 + c * i1v;
      }
    }
#pragma unroll
    for (int q = 0; q < 4; q++) {
      int mc = 8 >> q, mt = 8 >> ((q + 1) & 3);
#pragma unroll
      for (int i = 0; i < 16; i++) if ((i & mc) && !(i & mt)) {
        int i1 = i | mt;
        float tr = re[i]; re[i] = re[i1]; re[i1] = tr;
        float ti = im[i]; im[i] = im[i1]; im[i1] = ti;
      }
    }
#pragma unroll
    for (int q = 0; q < 4; q++) {
      float th = 0.5f * qp[d * 8 + 4 + q];
      float s, c; __sincosf(th, &s, &c);
      int m = 8 >> q;
#pragma unroll
      for (int i = 0; i < 16; i++) {
        float pi = (i & m) ? s : -s;
        float r0 = re[i], i0 = im[i];
        re[i] = r0 * c - i0 * pi;
        im[i] = r0 * pi + i0 * c;
      }
    }
  }

  float p[16];
#pragma unroll
  for (int i = 0; i < 16; i++) p[i] = re[i] * re[i] + im[i] * im[i];
  float z[4];
#pragma unroll
  for (int q = 0; q < 4; q++) {
    int m = 8 >> q; float acc = 0.f;
#pragma unroll
    for (int i = 0; i < 16; i++) acc += (i & m) ? -p[i] : p[i];
    z[q] = acc;
  }
  qout[r] = make_float4(z[0], z[1], z[2], z[3]);

  float st[14];
  st[0] = z[0]; st[1] = z[1]; st[2] = z[2]; st[3] = z[3];
  int p5 = 4;
#pragma unroll
  for (int a = 0; a < 4; a++)
#pragma unroll
    for (int b = a; b < 4; b++) st[p5++] = z[a] * z[b];

  __shared__ float part[4][14];
  int lane = tid & 63, wv = tid >> 6;
#pragma unroll
  for (int s = 0; s < 14; s++) {
    float v = st[s];
#pragma unroll
    for (int o = 32; o; o >>= 1) v += __shfl_down(v, o, 64);
    if (lane == 0) part[wv][s] = v;
  }
  __syncthreads();
  if (tid < 14)
    atomicAdd(stats + tid, part[0][tid] + part[1][tid] + part[2][tid] + part[3][tid]);
}

// ---------------- K2: fold BN1 into effective fc1 weights ----------------
__global__ void k_prep1(const float* __restrict__ w1, const float* __restrict__ b1,
                        const float* __restrict__ g, const float* __restrict__ bb,
                        const float* __restrict__ stats, float* __restrict__ w1e,
                        float* __restrict__ b1e, float invB)
{
  int j = threadIdx.x;   // 128
  float qb0 = stats[0] * invB, qb1 = stats[1] * invB, qb2 = stats[2] * invB, qb3 = stats[3] * invB;
  float M00 = stats[4] * invB, M01 = stats[5] * invB, M02 = stats[6] * invB, M03 = stats[7] * invB;
  float M11 = stats[8] * invB, M12 = stats[9] * invB, M13 = stats[10] * invB;
  float M22 = stats[11] * invB, M23 = stats[12] * invB, M33 = stats[13] * invB;
  float w0 = w1[j * 4 + 0], wv1 = w1[j * 4 + 1], wv2 = w1[j * 4 + 2], wv3 = w1[j * 4 + 3];
  float b = b1[j];
  float wq = w0 * qb0 + wv1 * qb1 + wv2 * qb2 + wv3 * qb3;
  float m = wq + b;
  float quad = w0 * w0 * M00 + wv1 * wv1 * M11 + wv2 * wv2 * M22 + wv3 * wv3 * M33
             + 2.f * (w0 * wv1 * M01 + w0 * wv2 * M02 + w0 * wv3 * M03
                    + wv1 * wv2 * M12 + wv1 * wv3 * M13 + wv2 * wv3 * M23);
  float e2 = quad + 2.f * b * wq + b * b;
  float var = e2 - m * m;
  float s = g[j] * rsqrtf(var + 1e-5f);
  w1e[j * 4 + 0] = s * w0; w1e[j * 4 + 1] = s * wv1;
  w1e[j * 4 + 2] = s * wv2; w1e[j * 4 + 3] = s * wv3;
  b1e[j] = s * b + bb[j] - s * m;
}

// ---------------- K2b: split weights into bf16 hi/lo pairs ----------------
__global__ __launch_bounds__(256) void k_prepw(
    const float* __restrict__ w2, const float* __restrict__ w3,
    unsigned short* __restrict__ w2h, unsigned short* __restrict__ w2l,
    unsigned short* __restrict__ w3h, unsigned short* __restrict__ w3l)
{
  int i = blockIdx.x * 256 + threadIdx.x;   // 0..65535
  if (i < 32768) split2(w2[i], &w2h[i], &w2l[i]);
  split2(w3[i], &w3h[i], &w3l[i]);
}

// ---------------- K3: fc2 via MFMA (split bf16) -> BN2 batch stats ----------------
// M-tile 128 rows/block, N = 256 (wave w owns cols [w*64, w*64+64))
__global__ __launch_bounds__(256, 2) void k_fc2stats(
    const float4* __restrict__ q, const float4* __restrict__ w1e4,
    const float* __restrict__ b1e,
    const unsigned short* __restrict__ w2h, const unsigned short* __restrict__ w2l,
    const float* __restrict__ b2,
    float* __restrict__ s2sum, float* __restrict__ s2sq)
{
  __shared__ __align__(16) float4 qs[128];                   // 2 KB
  __shared__ __align__(16) unsigned short a1h[128][136];     // 34.8 KB
  __shared__ __align__(16) unsigned short a1l[128][136];     // 34.8 KB

  int t = threadIdx.x;
  int lane = t & 63, w = t >> 6, q15 = lane & 15, quad = lane >> 4;
  size_t rowBase = (size_t)blockIdx.x * 128;

  if (t < 128) qs[t] = q[rowBase + t];
  __syncthreads();

  // ---- stage a1 = relu(W1e q + b1e), split into hi/lo bf16 ----
  {
    int j = t & 127;
    float4 w1 = w1e4[j];
    float b1v = b1e[j];
    int rb = (t >> 7) * 64;
#pragma unroll 4
    for (int i = 0; i < 64; i++) {
      float4 qv = qs[rb + i];
      float v = fmaf(w1.x, qv.x, fmaf(w1.y, qv.y, fmaf(w1.z, qv.z, fmaf(w1.w, qv.w, b1v))));
      float a = fmaxf(v, 0.f);
      split2(a, &a1h[rb + i][j], &a1l[rb + i][j]);
    }
  }
  __syncthreads();

  // ---- fc2 K-loop: h2 = a1 * W2^T (split-bf16 MFMA, 3 products) ----
  f32x4 acc[8][4];
#pragma unroll
  for (int mt = 0; mt < 8; mt++)
#pragma unroll
    for (int nt = 0; nt < 4; nt++) acc[mt][nt] = (f32x4){0.f, 0.f, 0.f, 0.f};

#pragma unroll
  for (int ks = 0; ks < 4; ks++) {
    int ka = ks * 32 + quad * 8;
    bf16x8 bh[4], bl[4];
#pragma unroll
    for (int nt = 0; nt < 4; nt++) {
      int col = w * 64 + nt * 16 + q15;
      bh[nt] = ldg_frag(w2h + (size_t)col * 128 + ka);
      bl[nt] = ldg_frag(w2l + (size_t)col * 128 + ka);
    }
#pragma unroll
    for (int mt = 0; mt < 8; mt++) {
      int ar = mt * 16 + q15;
      bf16x8 ah = *(const bf16x8*)&a1h[ar][ka];
      bf16x8 al = *(const bf16x8*)&a1l[ar][ka];
#pragma unroll
      for (int nt = 0; nt < 4; nt++) {
        acc[mt][nt] = MFMA(ah, bh[nt], acc[mt][nt]);
        acc[mt][nt] = MFMA(al, bh[nt], acc[mt][nt]);
        acc[mt][nt] = MFMA(ah, bl[nt], acc[mt][nt]);
      }
    }
  }

  // ---- stats epilogue: per-column sum & sumsq over the 128 rows ----
#pragma unroll
  for (int nt = 0; nt < 4; nt++) {
    int col = w * 64 + nt * 16 + q15;
    float b2v = b2[col];
    float s = 0.f, ss = 0.f;
#pragma unroll
    for (int mt = 0; mt < 8; mt++)
#pragma unroll
      for (int r = 0; r < 4; r++) {
        float h = acc[mt][nt][r] + b2v;
        s += h; ss += h * h;
      }
    s += __shfl_down(s, 32, 64);  s += __shfl_down(s, 16, 64);
    ss += __shfl_down(ss, 32, 64); ss += __shfl_down(ss, 16, 64);
    if (lane < 16) {
      atomicAdd(&s2sum[col], s);
      atomicAdd(&s2sq[col], ss);
    }
  }
}

// ---------------- K4: BN2 affine coefficients ----------------
__global__ void k_prep2(const float* __restrict__ g, const float* __restrict__ bb,
                        const float* __restrict__ s2sum, const float* __restrict__ s2sq,
                        float* __restrict__ sc2, float* __restrict__ t2, float invB)
{
  int j = threadIdx.x;   // 256
  float m = s2sum[j] * invB;
  float v = s2sq[j] * invB - m * m;
  float s = g[j] * rsqrtf(v + 1e-5f);
  sc2[j] = s;
  t2[j] = bb[j] - m * s;
}

// ---------------- K5: fc2 -> BN2+ReLU -> fc3 -> tanh (all MFMA) ----------------
// M-tile 64 rows/block; wave w owns cols [w*64, w*64+64)
__global__ __launch_bounds__(256, 2) void k_final(
    const float4* __restrict__ q, const float4* __restrict__ w1e4,
    const float* __restrict__ b1e,
    const unsigned short* __restrict__ w2h, const unsigned short* __restrict__ w2l,
    const float* __restrict__ b2,
    const float* __restrict__ sc2, const float* __restrict__ t2g,
    const unsigned short* __restrict__ w3h, const unsigned short* __restrict__ w3l,
    const float* __restrict__ b3, float* __restrict__ out)
{
  // phase1: a1h[64][136], a1l[64][136] (17.4 KB ea) aliased inside
  // phase2: a2h[64][264], a2l[64][264] (33.8 KB ea)
  __shared__ __align__(16) unsigned short smem[2 * 64 * 264];  // 67.6 KB
  __shared__ __align__(16) float4 qs[64];                      // 1 KB
  unsigned short* a1h = smem;
  unsigned short* a1l = smem + 64 * 136;
  unsigned short* a2h = smem;
  unsigned short* a2l = smem + 64 * 264;

  int t = threadIdx.x;
  int lane = t & 63, w = t >> 6, q15 = lane & 15, quad = lane >> 4;
  size_t rowBase = (size_t)blockIdx.x * 64;

  if (t < 64) qs[t] = q[rowBase + t];
  __syncthreads();

  // ---- stage a1 ----
  {
    int j = t & 127;
    float4 w1 = w1e4[j];
    float b1v = b1e[j];
    int rb = (t >> 7) * 32;
#pragma unroll 4
    for (int i = 0; i < 32; i++) {
      float4 qv = qs[rb + i];
      float v = fmaf(w1.x, qv.x, fmaf(w1.y, qv.y, fmaf(w1.z, qv.z, fmaf(w1.w, qv.w, b1v))));
      float a = fmaxf(v, 0.f);
      split2(a, &a1h[(rb + i) * 136 + j], &a1l[(rb + i) * 136 + j]);
    }
  }
  __syncthreads();

  // ---- fc2 K-loop ----
  f32x4 acc[4][4];
#pragma unroll
  for (int mt = 0; mt < 4; mt++)
#pragma unroll
    for (int nt = 0; nt < 4; nt++) acc[mt][nt] = (f32x4){0.f, 0.f, 0.f, 0.f};

#pragma unroll
  for (int ks = 0; ks < 4; ks++) {
    int ka = ks * 32 + quad * 8;
    bf16x8 bh[4], bl[4];
#pragma unroll
    for (int nt = 0; nt < 4; nt++) {
      int col = w * 64 + nt * 16 + q15;
      bh[nt] = ldg_frag(w2h + (size_t)col * 128 + ka);
      bl[nt] = ldg_frag(w2l + (size_t)col * 128 + ka);
    }
#pragma unroll
    for (int mt = 0; mt < 4; mt++) {
      int ar = mt * 16 + q15;
      bf16x8 ah = *(const bf16x8*)&a1h[ar * 136 + ka];
      bf16x8 al = *(const bf16x8*)&a1l[ar * 136 + ka];
#pragma unroll
      for (int nt = 0; nt < 4; nt++) {
        acc[mt][nt] = MFMA(ah, bh[nt], acc[mt][nt]);
        acc[mt][nt] = MFMA(al, bh[nt], acc[mt][nt]);
        acc[mt][nt] = MFMA(ah, bl[nt], acc[mt][nt]);
      }
    }
  }
  __syncthreads();   // all a1 reads done; safe to overwrite with a2

  // ---- BN2 + ReLU, split to bf16, write a2 to LDS ----
#pragma unroll
  for (int nt = 0; nt < 4; nt++) {
    int col = w * 64 + nt * 16 + q15;
    float b2v = b2[col], sv = sc2[col], tv = t2g[col];
#pragma unroll
    for (int mt = 0; mt < 4; mt++)
#pragma unroll
      for (int r = 0; r < 4; r++) {
        int row = mt * 16 + quad * 4 + r;
        float h = acc[mt][nt][r] + b2v;
        float a = fmaxf(fmaf(h, sv, tv), 0.f);
        split2(a, &a2h[row * 264 + col], &a2l[row * 264 + col]);
      }
  }
  __syncthreads();

  // ---- fc3 K-loop (K=256) ----
  f32x4 acc3[4][4];
#pragma unroll
  for (int mt = 0; mt < 4; mt++)
#pragma unroll
    for (int nt = 0; nt < 4; nt++) acc3[mt][nt] = (f32x4){0.f, 0.f, 0.f, 0.f};

#pragma unroll
  for (int ks = 0; ks < 8; ks++) {
    int ka = ks * 32 + quad * 8;
    bf16x8 bh[4], bl[4];
#pragma unroll
    for (int nt = 0; nt < 4; nt++) {
      int col = w * 64 + nt * 16 + q15;
      bh[nt] = ldg_frag(w3h + (size_t)col * 256 + ka);
      bl[nt] = ldg_frag(w3l + (size_t)col * 256 + ka);
    }
#pragma unroll
    for (int mt = 0; mt < 4; mt++) {
      int ar = mt * 16 + q15;
      bf16x8 ah = *(const bf16x8*)&a2h[ar * 264 + ka];
      bf16x8 al = *(const bf16x8*)&a2l[ar * 264 + ka];
#pragma unroll
      for (int nt = 0; nt < 4; nt++) {
        acc3[mt][nt] = MFMA(ah, bh[nt], acc3[mt][nt]);
        acc3[mt][nt] = MFMA(al, bh[nt], acc3[mt][nt]);
        acc3[mt][nt] = MFMA(ah, bl[nt], acc3[mt][nt]);
      }
    }
  }

  // ---- tanh epilogue + store ----
#pragma unroll
  for (int nt = 0; nt < 4; nt++) {
    int col = w * 64 + nt * 16 + q15;
    float b3v = b3[col];
#pragma unroll
    for (int mt = 0; mt < 4; mt++)
#pragma unroll
      for (int r = 0; r < 4; r++) {
        int row = mt * 16 + quad * 4 + r;
        out[(rowBase + row) * 256 + col] = tanh_fast(acc3[mt][nt][r] + b3v);
      }
  }
}

// ---------------- host launcher ----------------
extern "C" void kernel_launch(void* const* d_in, const int* in_sizes, int n_in,
                              void* d_out, int out_size, void* d_ws, size_t ws_size,
                              hipStream_t stream) {
  const float* x     = (const float*)d_in[0];
  const float* qp    = (const float*)d_in[1];
  const float* fc1_w = (const float*)d_in[2];
  const float* fc1_b = (const float*)d_in[3];
  const float* bn1_g = (const float*)d_in[4];
  const float* bn1_b = (const float*)d_in[5];
  const float* fc2_w = (const float*)d_in[6];
  const float* fc2_b = (const float*)d_in[7];
  const float* bn2_g = (const float*)d_in[8];
  const float* bn2_b = (const float*)d_in[9];
  const float* fc3_w = (const float*)d_in[10];
  const float* fc3_b = (const float*)d_in[11];
  float* out = (float*)d_out;
  float* ws  = (float*)d_ws;

  int B = in_sizes[0] / 4;

  // ws layout: q[B*4] f32 | stats1[16] | w1e[512] | b1e[128] | s2sum[256] |
  //            s2sq[256] | sc2[256] | t2[256] | w2h/w2l[32768] us | w3h/w3l[65536] us
  float* wq    = ws;
  float* s1    = ws + (size_t)4 * B;
  float* w1e   = s1 + 16;
  float* b1e   = w1e + 512;
  float* s2sum = b1e + 128;
  float* s2sq  = s2sum + 256;
  float* sc2   = s2sq + 256;
  float* t2    = sc2 + 256;
  unsigned short* w2h = (unsigned short*)(t2 + 256);
  unsigned short* w2l = w2h + 32768;
  unsigned short* w3h = w2l + 32768;
  unsigned short* w3l = w3h + 65536;

  // zero accumulator region: stats1(16) + w1e(512) + b1e(128) + s2sum(256) + s2sq(256)
  hipMemsetAsync((void*)s1, 0, (16 + 512 + 128 + 256 + 256) * sizeof(float), stream);

  float invB = 1.0f / (float)B;

  k_quantum<<<B / 256, 256, 0, stream>>>((const float4*)x, qp, (float4*)wq, s1);
  k_prepw<<<256, 256, 0, stream>>>(fc2_w, fc3_w, w2h, w2l, w3h, w3l);
  k_prep1<<<1, 128, 0, stream>>>(fc1_w, fc1_b, bn1_g, bn1_b, s1, w1e, b1e, invB);
  k_fc2stats<<<B / 128, 256, 0, stream>>>((const float4*)wq, (const float4*)w1e, b1e,
                                          w2h, w2l, fc2_b, s2sum, s2sq);
  k_prep2<<<1, 256, 0, stream>>>(bn2_g, bn2_b, s2sum, s2sq, sc2, t2, invB);
  k_final<<<B / 64, 256, 0, stream>>>((const float4*)wq, (const float4*)w1e, b1e,
                                      w2h, w2l, fc2_b, sc2, t2, w3h, w3l, fc3_b, out);
}

// Round 3
// 149.049 us; speedup vs baseline: 5.0345x; 1.3507x over previous
//
#include <hip/hip_runtime.h>

typedef __attribute__((ext_vector_type(8))) _Float16 f16x8;
typedef __attribute__((ext_vector_type(16))) float f32x16;

#define MFMA32(a, b, c) __builtin_amdgcn_mfma_f32_32x32x16_f16((a), (b), (c), 0, 0, 0)

// ---------------- helpers ----------------
__device__ __forceinline__ float tanh_fast(float x) {
  return 1.0f - 2.0f / (__expf(2.0f * x) + 1.0f);
}

// ---------------- K1: quantum sim + q-moments; tail blocks convert weights ----------------
__global__ __launch_bounds__(256) void k_quantum(
    const float4* __restrict__ x, const float* __restrict__ qp,
    float4* __restrict__ qout, float* __restrict__ stats, int QB,
    const float* __restrict__ w2, const float* __restrict__ w3,
    _Float16* __restrict__ w2f, _Float16* __restrict__ w3f)
{
  int tid = threadIdx.x;

  if (blockIdx.x >= QB) {   // weight-conversion tail blocks (256 of them)
    int i = (blockIdx.x - QB) * 256 + tid;   // 0..65535
    w3f[i] = (_Float16)w3[i];
    if (i < 32768) w2f[i] = (_Float16)w2[i];
    return;
  }

  size_t r = (size_t)blockIdx.x * 256 + tid;
  float4 xr = x[r];
  float xv[4] = {xr.x, xr.y, xr.z, xr.w};

  float re[16], im[16];
#pragma unroll
  for (int i = 0; i < 16; i++) { re[i] = 0.f; im[i] = 0.f; }
  re[0] = 1.f;

#pragma unroll
  for (int d = 0; d < 3; d++) {
#pragma unroll
    for (int q = 0; q < 4; q++) {
      float th = 0.5f * (xv[q] + qp[d * 8 + q]);
      float s, c; __sincosf(th, &s, &c);
      int m = 8 >> q;
#pragma unroll
      for (int i = 0; i < 16; i++) if (!(i & m)) {
        int i1 = i | m;
        float r0 = re[i], i0 = im[i], r1 = re[i1], i1v = im[i1];
        re[i]  = c * r0 - s * r1;  im[i]  = c * i0 - s * i1v;
        re[i1] = s * r0 + c * r1;  im[i1] = s * i0 + c * i1v;
      }
    }
#pragma unroll
    for (int q = 0; q < 4; q++) {
      int mc = 8 >> q, mt = 8 >> ((q + 1) & 3);
#pragma unroll
      for (int i = 0; i < 16; i++) if ((i & mc) && !(i & mt)) {
        int i1 = i | mt;
        float tr = re[i]; re[i] = re[i1]; re[i1] = tr;
        float ti = im[i]; im[i] = im[i1]; im[i1] = ti;
      }
    }
#pragma unroll
    for (int q = 0; q < 4; q++) {
      float th = 0.5f * qp[d * 8 + 4 + q];
      float s, c; __sincosf(th, &s, &c);
      int m = 8 >> q;
#pragma unroll
      for (int i = 0; i < 16; i++) {
        float pi = (i & m) ? s : -s;
        float r0 = re[i], i0 = im[i];
        re[i] = r0 * c - i0 * pi;
        im[i] = r0 * pi + i0 * c;
      }
    }
  }

  float p[16];
#pragma unroll
  for (int i = 0; i < 16; i++) p[i] = re[i] * re[i] + im[i] * im[i];
  float z[4];
#pragma unroll
  for (int q = 0; q < 4; q++) {
    int m = 8 >> q; float acc = 0.f;
#pragma unroll
    for (int i = 0; i < 16; i++) acc += (i & m) ? -p[i] : p[i];
    z[q] = acc;
  }
  qout[r] = make_float4(z[0], z[1], z[2], z[3]);

  float st[14];
  st[0] = z[0]; st[1] = z[1]; st[2] = z[2]; st[3] = z[3];
  int p5 = 4;
#pragma unroll
  for (int a = 0; a < 4; a++)
#pragma unroll
    for (int b = a; b < 4; b++) st[p5++] = z[a] * z[b];

  __shared__ float part[4][14];
  int lane = tid & 63, wv = tid >> 6;
#pragma unroll
  for (int s = 0; s < 14; s++) {
    float v = st[s];
#pragma unroll
    for (int o = 32; o; o >>= 1) v += __shfl_down(v, o, 64);
    if (lane == 0) part[wv][s] = v;
  }
  __syncthreads();
  if (tid < 14)
    atomicAdd(stats + tid, part[0][tid] + part[1][tid] + part[2][tid] + part[3][tid]);
}

// ---------------- K2: fold BN1 into effective fc1 weights ----------------
__global__ void k_prep1(const float* __restrict__ w1, const float* __restrict__ b1,
                        const float* __restrict__ g, const float* __restrict__ bb,
                        const float* __restrict__ stats, float* __restrict__ w1e,
                        float* __restrict__ b1e, float invB)
{
  int j = threadIdx.x;   // 128
  float qb0 = stats[0] * invB, qb1 = stats[1] * invB, qb2 = stats[2] * invB, qb3 = stats[3] * invB;
  float M00 = stats[4] * invB, M01 = stats[5] * invB, M02 = stats[6] * invB, M03 = stats[7] * invB;
  float M11 = stats[8] * invB, M12 = stats[9] * invB, M13 = stats[10] * invB;
  float M22 = stats[11] * invB, M23 = stats[12] * invB, M33 = stats[13] * invB;
  float w0 = w1[j * 4 + 0], wv1 = w1[j * 4 + 1], wv2 = w1[j * 4 + 2], wv3 = w1[j * 4 + 3];
  float b = b1[j];
  float wq = w0 * qb0 + wv1 * qb1 + wv2 * qb2 + wv3 * qb3;
  float m = wq + b;
  float quad = w0 * w0 * M00 + wv1 * wv1 * M11 + wv2 * wv2 * M22 + wv3 * wv3 * M33
             + 2.f * (w0 * wv1 * M01 + w0 * wv2 * M02 + w0 * wv3 * M03
                    + wv1 * wv2 * M12 + wv1 * wv3 * M13 + wv2 * wv3 * M23);
  float e2 = quad + 2.f * b * wq + b * b;
  float var = e2 - m * m;
  float s = g[j] * rsqrtf(var + 1e-5f);
  w1e[j * 4 + 0] = s * w0; w1e[j * 4 + 1] = s * wv1;
  w1e[j * 4 + 2] = s * wv2; w1e[j * 4 + 3] = s * wv3;
  b1e[j] = s * b + bb[j] - s * m;
}

// ---------------- K3: fc2 via fp16 32x32x16 MFMA -> BN2 batch stats ----------------
// 128 rows/block; wave w owns cols [w*64, w*64+64) as two 32-col groups
__global__ __launch_bounds__(256, 2) void k_fc2stats(
    const float4* __restrict__ q, const float4* __restrict__ w1e4,
    const float* __restrict__ b1e, const _Float16* __restrict__ w2f,
    const float* __restrict__ b2,
    float* __restrict__ s2sum, float* __restrict__ s2sq)
{
  __shared__ __align__(16) float4 qs[128];                 // 2 KB
  __shared__ __align__(16) _Float16 a1[128 * 136];         // 34.8 KB

  int t = threadIdx.x;
  int lane = t & 63, w = t >> 6, m32 = lane & 31, hh = lane >> 5;
  size_t rowBase = (size_t)blockIdx.x * 128;

  if (t < 128) qs[t] = q[rowBase + t];
  __syncthreads();

  // stage a1 = relu(W1e q + b1e) as fp16
  {
    int j = t & 127;
    float4 w1 = w1e4[j];
    float b1v = b1e[j];
    int rb = (t >> 7) * 64;
#pragma unroll 8
    for (int i = 0; i < 64; i++) {
      float4 qv = qs[rb + i];
      float v = fmaf(w1.x, qv.x, fmaf(w1.y, qv.y, fmaf(w1.z, qv.z, fmaf(w1.w, qv.w, b1v))));
      a1[(rb + i) * 136 + j] = (_Float16)fmaxf(v, 0.f);
    }
  }
  __syncthreads();

  f32x16 acc[4][2];
#pragma unroll
  for (int mt = 0; mt < 4; mt++)
#pragma unroll
    for (int nt = 0; nt < 2; nt++)
#pragma unroll
      for (int r = 0; r < 16; r++) acc[mt][nt][r] = 0.f;

#pragma unroll
  for (int ks = 0; ks < 8; ks++) {               // K = 128, step 16
    int kb = ks * 16 + hh * 8;
    f16x8 bfr[2];
#pragma unroll
    for (int nt = 0; nt < 2; nt++)
      bfr[nt] = *(const f16x8*)(w2f + (size_t)(w * 64 + nt * 32 + m32) * 128 + kb);
#pragma unroll
    for (int mt = 0; mt < 4; mt++) {
      f16x8 afr = *(const f16x8*)&a1[(mt * 32 + m32) * 136 + kb];
#pragma unroll
      for (int nt = 0; nt < 2; nt++)
        acc[mt][nt] = MFMA32(afr, bfr[nt], acc[mt][nt]);
    }
  }

  // per-column sum & sumsq of h2 = acc + b2 over the block's 128 rows
#pragma unroll
  for (int nt = 0; nt < 2; nt++) {
    int col = w * 64 + nt * 32 + m32;
    float b2v = b2[col];
    float s = 0.f, ss = 0.f;
#pragma unroll
    for (int mt = 0; mt < 4; mt++)
#pragma unroll
      for (int r = 0; r < 16; r++) {
        float hv = acc[mt][nt][r] + b2v;
        s += hv; ss += hv * hv;
      }
    s += __shfl_down(s, 32, 64);
    ss += __shfl_down(ss, 32, 64);
    if (lane < 32) {
      atomicAdd(&s2sum[col], s);
      atomicAdd(&s2sq[col], ss);
    }
  }
}

// ---------------- K4: BN2 affine coefficients (b2 folded in) ----------------
__global__ void k_prep2(const float* __restrict__ g, const float* __restrict__ bb,
                        const float* __restrict__ b2,
                        const float* __restrict__ s2sum, const float* __restrict__ s2sq,
                        float* __restrict__ sc2, float* __restrict__ t2, float invB)
{
  int j = threadIdx.x;   // 256
  float m = s2sum[j] * invB;
  float v = s2sq[j] * invB - m * m;
  float s = g[j] * rsqrtf(v + 1e-5f);
  sc2[j] = s;
  t2[j] = bb[j] - m * s + b2[j] * s;   // a2 = relu(s*h_nobias + t2)
}

// ---------------- K5: fc2 -> BN2+ReLU -> fc3 -> tanh (fp16 32x32 MFMA) ----------------
// 128 rows/block; wave w owns cols [w*64, w*64+64)
__global__ __launch_bounds__(256, 2) void k_final(
    const float4* __restrict__ q, const float4* __restrict__ w1e4,
    const float* __restrict__ b1e, const _Float16* __restrict__ w2f,
    const float* __restrict__ sc2, const float* __restrict__ t2g,
    const _Float16* __restrict__ w3f, const float* __restrict__ b3,
    float* __restrict__ out)
{
  __shared__ __align__(16) float4 qs[128];                 // 2 KB
  __shared__ __align__(16) _Float16 un[128 * 264];         // 66 KB union
  _Float16* a1 = un;    // [128][136] during fc2 phase
  _Float16* a2 = un;    // [128][264] during fc3 phase

  int t = threadIdx.x;
  int lane = t & 63, w = t >> 6, m32 = lane & 31, hh = lane >> 5;
  size_t rowBase = (size_t)blockIdx.x * 128;

  if (t < 128) qs[t] = q[rowBase + t];
  __syncthreads();

  // ---- stage a1 ----
  {
    int j = t & 127;
    float4 w1 = w1e4[j];
    float b1v = b1e[j];
    int rb = (t >> 7) * 64;
#pragma unroll 8
    for (int i = 0; i < 64; i++) {
      float4 qv = qs[rb + i];
      float v = fmaf(w1.x, qv.x, fmaf(w1.y, qv.y, fmaf(w1.z, qv.z, fmaf(w1.w, qv.w, b1v))));
      a1[(rb + i) * 136 + j] = (_Float16)fmaxf(v, 0.f);
    }
  }
  __syncthreads();

  // ---- fc2 ----
  f32x16 acc[4][2];
#pragma unroll
  for (int mt = 0; mt < 4; mt++)
#pragma unroll
    for (int nt = 0; nt < 2; nt++)
#pragma unroll
      for (int r = 0; r < 16; r++) acc[mt][nt][r] = 0.f;

#pragma unroll
  for (int ks = 0; ks < 8; ks++) {
    int kb = ks * 16 + hh * 8;
    f16x8 bfr[2];
#pragma unroll
    for (int nt = 0; nt < 2; nt++)
      bfr[nt] = *(const f16x8*)(w2f + (size_t)(w * 64 + nt * 32 + m32) * 128 + kb);
#pragma unroll
    for (int mt = 0; mt < 4; mt++) {
      f16x8 afr = *(const f16x8*)&a1[(mt * 32 + m32) * 136 + kb];
#pragma unroll
      for (int nt = 0; nt < 2; nt++)
        acc[mt][nt] = MFMA32(afr, bfr[nt], acc[mt][nt]);
    }
  }
  __syncthreads();   // all a1 reads done; union becomes a2

  // ---- BN2 + ReLU -> a2 (fp16) ----
#pragma unroll
  for (int nt = 0; nt < 2; nt++) {
    int col = w * 64 + nt * 32 + m32;
    float sv = sc2[col], tv = t2g[col];
#pragma unroll
    for (int mt = 0; mt < 4; mt++)
#pragma unroll
      for (int r = 0; r < 16; r++) {
        int row = mt * 32 + (r & 3) + 8 * (r >> 2) + 4 * hh;
        a2[row * 264 + col] = (_Float16)fmaxf(fmaf(acc[mt][nt][r], sv, tv), 0.f);
      }
  }
  __syncthreads();

  // ---- fc3 (K = 256) ----
  f32x16 acc3[4][2];
#pragma unroll
  for (int mt = 0; mt < 4; mt++)
#pragma unroll
    for (int nt = 0; nt < 2; nt++)
#pragma unroll
      for (int r = 0; r < 16; r++) acc3[mt][nt][r] = 0.f;

#pragma unroll
  for (int ks = 0; ks < 16; ks++) {
    int kb = ks * 16 + hh * 8;
    f16x8 bfr[2];
#pragma unroll
    for (int nt = 0; nt < 2; nt++)
      bfr[nt] = *(const f16x8*)(w3f + (size_t)(w * 64 + nt * 32 + m32) * 256 + kb);
#pragma unroll
    for (int mt = 0; mt < 4; mt++) {
      f16x8 afr = *(const f16x8*)&a2[(mt * 32 + m32) * 264 + kb];
#pragma unroll
      for (int nt = 0; nt < 2; nt++)
        acc3[mt][nt] = MFMA32(afr, bfr[nt], acc3[mt][nt]);
    }
  }

  // ---- tanh epilogue: stores are 2x128B full lines per instruction ----
#pragma unroll
  for (int nt = 0; nt < 2; nt++) {
    int col = w * 64 + nt * 32 + m32;
    float b3v = b3[col];
#pragma unroll
    for (int mt = 0; mt < 4; mt++)
#pragma unroll
      for (int r = 0; r < 16; r++) {
        int row = mt * 32 + (r & 3) + 8 * (r >> 2) + 4 * hh;
        out[(rowBase + row) * 256 + col] = tanh_fast(acc3[mt][nt][r] + b3v);
      }
  }
}

// ---------------- host launcher ----------------
extern "C" void kernel_launch(void* const* d_in, const int* in_sizes, int n_in,
                              void* d_out, int out_size, void* d_ws, size_t ws_size,
                              hipStream_t stream) {
  const float* x     = (const float*)d_in[0];
  const float* qp    = (const float*)d_in[1];
  const float* fc1_w = (const float*)d_in[2];
  const float* fc1_b = (const float*)d_in[3];
  const float* bn1_g = (const float*)d_in[4];
  const float* bn1_b = (const float*)d_in[5];
  const float* fc2_w = (const float*)d_in[6];
  const float* fc2_b = (const float*)d_in[7];
  const float* bn2_g = (const float*)d_in[8];
  const float* bn2_b = (const float*)d_in[9];
  const float* fc3_w = (const float*)d_in[10];
  const float* fc3_b = (const float*)d_in[11];
  float* out = (float*)d_out;
  float* ws  = (float*)d_ws;

  int B = in_sizes[0] / 4;
  int QB = B / 256;

  // ws layout: q[B*4] f32 | stats1[16] | w1e[512] | b1e[128] | s2sum[256] |
  //            s2sq[256] | sc2[256] | t2[256] | w2f[32768] f16 | w3f[65536] f16
  float* wq    = ws;
  float* s1    = ws + (size_t)4 * B;
  float* w1e   = s1 + 16;
  float* b1e   = w1e + 512;
  float* s2sum = b1e + 128;
  float* s2sq  = s2sum + 256;
  float* sc2   = s2sq + 256;
  float* t2    = sc2 + 256;
  _Float16* w2f = (_Float16*)(t2 + 256);
  _Float16* w3f = w2f + 32768;

  hipMemsetAsync((void*)s1, 0, (16 + 512 + 128 + 256 + 256) * sizeof(float), stream);

  float invB = 1.0f / (float)B;

  k_quantum<<<QB + 256, 256, 0, stream>>>((const float4*)x, qp, (float4*)wq, s1, QB,
                                          fc2_w, fc3_w, w2f, w3f);
  k_prep1<<<1, 128, 0, stream>>>(fc1_w, fc1_b, bn1_g, bn1_b, s1, w1e, b1e, invB);
  k_fc2stats<<<B / 128, 256, 0, stream>>>((const float4*)wq, (const float4*)w1e, b1e,
                                          w2f, fc2_b, s2sum, s2sq);
  k_prep2<<<1, 256, 0, stream>>>(bn2_g, bn2_b, fc2_b, s2sum, s2sq, sc2, t2, invB);
  k_final<<<B / 128, 256, 0, stream>>>((const float4*)wq, (const float4*)w1e, b1e,
                                       w2f, sc2, t2, w3f, fc3_b, out);
}